// Round 2
// baseline (405.630 us; speedup 1.0000x reference)
//
#include <hip/hip_runtime.h>

#define NUM_BINS 15
#define NB 2048            // blocks; each owns a contiguous 4096-float4 chunk (64 KB/array)
#define NT 256
#define INV15 0.066666667f

// native clang vector types
typedef float vfloat4 __attribute__((ext_vector_type(4)));
typedef int   vint4   __attribute__((ext_vector_type(4)));

// One uint32 per element: [31:24] label, [23:16] 1, [15:0] round((p-bin/15)*4096).
// Per-thread totals (64 elem): cnt<=64, acc<=64, res<=64*274=17536 -> no field overflow.
__device__ __forceinline__ unsigned pack_elem(float pv, int lv, int* bin_out) {
    int bin = (int)ceilf(pv * 15.0f) - 1;      // matches jnp ceil(p*15)-1 in fp32
    bin = (min(max(bin, -1), 15)) & 15;        // invalid (p<=0 | p>1) -> 15 (dump row)
    *bin_out = bin;
    float x = fmaf(pv, 4096.0f, fmaf((float)bin, -4096.0f * INV15, 0.5f));
    unsigned rq = (unsigned)x;                 // v_cvt_u32_f32 saturates negatives to 0
    return ((unsigned)lv << 24) + 0x10000u + rq;
}

struct Batch { vfloat4 p0, p1; vint4 l0, l1; };

// Plain (cached) loads: inputs are rewritten by the harness restore-copy right
// before each iteration, so much of the 256 MiB is L3-resident. nt would bypass it.
__device__ __forceinline__ void load_batch(Batch& b, const vfloat4* __restrict__ p4,
                                           const vint4* __restrict__ l4, int j, int t) {
    const int o = (j << 9) + t;
    b.p0 = p4[o];
    b.p1 = p4[o + 256];
    b.l0 = l4[o];
    b.l1 = l4[o + 256];
}

// Fire-and-forget LDS atomics (ds_add_u32 no-return): no ds_read/lgkmcnt chain,
// no duplicate-bin merge. Bank = t%32 -> conflict-free (2-way wave64 aliasing is free).
__device__ __forceinline__ void scatter4(unsigned* histT, vfloat4 p, vint4 l) {
    int b0, b1, b2, b3;
    unsigned k0 = pack_elem(p.x, l.x, &b0);
    unsigned k1 = pack_elem(p.y, l.y, &b1);
    unsigned k2 = pack_elem(p.z, l.z, &b2);
    unsigned k3 = pack_elem(p.w, l.w, &b3);
    atomicAdd(&histT[b0 << 8], k0);
    atomicAdd(&histT[b1 << 8], k1);
    atomicAdd(&histT[b2 << 8], k2);
    atomicAdd(&histT[b3 << 8], k3);
}

__device__ __forceinline__ void consume(const Batch& b, unsigned* histT) {
    scatter4(histT, b.p0, b.l0);
    scatter4(histT, b.p1, b.l1);
}

// ws layout: float gsum[45] = cnt[15] | acc[15] | conf[15]; unsigned counter at ws+48.
// Host zeroes the first 256 B with hipMemsetAsync before this kernel.
__global__ __launch_bounds__(NT, 6) void ece_fused(
    const float* __restrict__ probs, const int* __restrict__ labels,
    float* __restrict__ ws, float* __restrict__ out, int n4, float inv_n)
{
    __shared__ unsigned hist[16 * NT];   // 16 KB: cell[bin][t]
    const int t = threadIdx.x;

    uint4* h4 = (uint4*)hist;
#pragma unroll
    for (int i = 0; i < 4; ++i) h4[i * NT + t] = uint4{0u, 0u, 0u, 0u};
    __syncthreads();

    const int base = blockIdx.x * 4096;          // float4 units
    const vfloat4* __restrict__ p4 = (const vfloat4*)probs + base;
    const vint4*   __restrict__ l4 = (const vint4*)labels + base;
    unsigned* histT = hist + t;

    if (base + 4096 <= n4) {
        // 8 batches, 2-deep double buffer: 8 loads in flight while consuming.
        Batch A, B;
        load_batch(A, p4, l4, 0, t);
        load_batch(B, p4, l4, 1, t);
        __builtin_amdgcn_sched_barrier(0);
        consume(A, histT); load_batch(A, p4, l4, 2, t);
        __builtin_amdgcn_sched_barrier(0);
        consume(B, histT); load_batch(B, p4, l4, 3, t);
        __builtin_amdgcn_sched_barrier(0);
        consume(A, histT); load_batch(A, p4, l4, 4, t);
        __builtin_amdgcn_sched_barrier(0);
        consume(B, histT); load_batch(B, p4, l4, 5, t);
        __builtin_amdgcn_sched_barrier(0);
        consume(A, histT); load_batch(A, p4, l4, 6, t);
        __builtin_amdgcn_sched_barrier(0);
        consume(B, histT); load_batch(B, p4, l4, 7, t);
        __builtin_amdgcn_sched_barrier(0);
        consume(A, histT);
        consume(B, histT);
    } else {
        // guarded tail path (unused at N=2^25; kept for generality)
        for (int j = 0; j < 16; ++j) {
            const int idx = (j << 8) + t;
            if (base + idx < n4) {
                vfloat4 p = p4[idx];
                vint4   l = l4[idx];
                scatter4(histT, p, l);
            }
        }
    }
    __syncthreads();

    // cross-thread reduce: row r = t>>4 (0..15), strip s = t&15 (16 cells each)
    const int r = t >> 4, s = t & 15;
    float csum = 0.f, asum = 0.f, rsum = 0.f;
#pragma unroll
    for (int k = 0; k < 16; ++k) {
        unsigned v = hist[(r << 8) + (s << 4) + k];
        asum += (float)(v >> 24);
        csum += (float)((v >> 16) & 0xFFu);
        rsum += (float)(v & 0xFFFFu);
    }
#pragma unroll
    for (int o = 8; o; o >>= 1) {    // 16-lane strips are wave-aligned
        csum += __shfl_down(csum, o);
        asum += __shfl_down(asum, o);
        rsum += __shfl_down(rsum, o);
    }
    if (s == 0 && r < NUM_BINS) {
        float conf = fmaf(csum, (float)r * INV15, rsum * 2.44140625e-4f);
        atomicAdd(&ws[r], csum);                 // device-scope fp32 atomics: cnt/acc are
        atomicAdd(&ws[NUM_BINS + r], asum);      // integer-valued (exact); conf order-
        atomicAdd(&ws[2 * NUM_BINS + r], conf);  // nondeterminism ~1e-9 relative.
    }

    // last-block-drains: ticket counter at ws+48
    __syncthreads();                 // s_waitcnt vmcnt(0) before barrier: atomics complete
    if (t == 0) {
        __threadfence();
        unsigned* ctr = (unsigned*)ws + 48;
        unsigned old = atomicAdd(ctr, 1u);
        hist[0] = (old == NB - 1) ? 1u : 0u;
    }
    __syncthreads();

    if (hist[0]) {
        float term = 0.f;
        if (t < NUM_BINS) {
            float c  = atomicAdd(&ws[t], 0.f);               // coherent read
            float a  = atomicAdd(&ws[NUM_BINS + t], 0.f);
            float cf = atomicAdd(&ws[2 * NUM_BINS + t], 0.f);
            float denom = fmaxf(c, 1.f);
            term = (c * inv_n) * fabsf(a / denom - cf / denom);
        }
        if (t < 64) {                // lanes 0..14 of wave 0 hold the terms
#pragma unroll
            for (int o = 8; o; o >>= 1) term += __shfl_down(term, o);
            if (t == 0) out[0] = term;
        }
    }
}

extern "C" void kernel_launch(void* const* d_in, const int* in_sizes, int n_in,
                              void* d_out, int out_size, void* d_ws, size_t ws_size,
                              hipStream_t stream)
{
    const float* probs  = (const float*)d_in[0];
    const int*   labels = (const int*)d_in[1];
    const int n = in_sizes[0];   // 33,554,432

    hipMemsetAsync(d_ws, 0, 256, stream);   // gsum[45] + counter (graph-capturable)
    ece_fused<<<NB, NT, 0, stream>>>(probs, labels, (float*)d_ws, (float*)d_out,
                                     n / 4, 1.0f / (float)n);
}

// Round 3
// 283.556 us; speedup vs baseline: 1.4305x; 1.4305x over previous
//
#include <hip/hip_runtime.h>

#define NUM_BINS 15
#define NB 2048            // blocks; each owns a contiguous 4096-float4 chunk (64 KB/array)
#define NT 256
#define NCOMP 45           // ws rows: cnt[15] | acc[15] | conf[15]
#define INV15 0.066666667f

// native clang vector types
typedef float vfloat4 __attribute__((ext_vector_type(4)));
typedef int   vint4   __attribute__((ext_vector_type(4)));

// One uint32 per element: [31:24] label, [23:16] 1, [15:0] round((p-bin/15)*4096).
// Per-thread totals (64 elem): cnt<=64, acc<=64, res<=64*274=17536 -> no field overflow.
__device__ __forceinline__ unsigned pack_elem(float pv, int lv, int* bin_out) {
    int bin = (int)ceilf(pv * 15.0f) - 1;      // matches jnp ceil(p*15)-1 in fp32
    bin = (min(max(bin, -1), 15)) & 15;        // invalid (p<=0 | p>1) -> 15 (dump row)
    *bin_out = bin;
    float x = fmaf(pv, 4096.0f, fmaf((float)bin, -4096.0f * INV15, 0.5f));
    unsigned rq = (unsigned)x;                 // v_cvt_u32_f32 saturates negatives to 0
    return ((unsigned)lv << 24) + 0x10000u + rq;
}

// Inline-asm cached global loads: opaque to the compiler, so (a) they CANNOT be
// rematerialized at use points (round-2 failure: plain loads collapsed the double
// buffer to VGPR_Count=24), and (b) no automatic s_waitcnt vmcnt(0) is inserted —
// we count vmcnt by hand. Cached (no nt): restore-copy leaves inputs L2/L3-hot
// (round-2 FETCH_SIZE showed 134 of 268 MB served by cache).
__device__ __forceinline__ vfloat4 gload_f4(const float* base, unsigned voff) {
    vfloat4 r;
    asm volatile("global_load_dwordx4 %0, %1, %2"
                 : "=v"(r) : "v"(voff), "s"(base) : "memory");
    return r;
}
__device__ __forceinline__ vint4 gload_i4(const int* base, unsigned voff) {
    vint4 r;
    asm volatile("global_load_dwordx4 %0, %1, %2"
                 : "=v"(r) : "v"(voff), "s"(base) : "memory");
    return r;
}

struct Batch { vfloat4 p0, p1, p2, p3; vint4 l0, l1, l2, l3; };

// 8 loads/batch. Bases are wave-uniform (SGPR pairs, hoisted once); the per-lane
// part is a single 32-bit voffset = t*16 + j*16384 bytes.
__device__ __forceinline__ void load_batch(Batch& b, const float* __restrict__ p,
                                           const int* __restrict__ l, unsigned voff) {
    b.p0 = gload_f4(p,        voff);
    b.p1 = gload_f4(p + 1024, voff);   // +4096 B (256 float4)
    b.p2 = gload_f4(p + 2048, voff);
    b.p3 = gload_f4(p + 3072, voff);
    b.l0 = gload_i4(l,        voff);
    b.l1 = gload_i4(l + 1024, voff);
    b.l2 = gload_i4(l + 2048, voff);
    b.l3 = gload_i4(l + 3072, voff);
}

#define WAIT_VM8()  do { asm volatile("s_waitcnt vmcnt(8)" ::: "memory"); \
                         __builtin_amdgcn_sched_barrier(0); } while (0)
#define WAIT_VM0()  do { asm volatile("s_waitcnt vmcnt(0)" ::: "memory"); \
                         __builtin_amdgcn_sched_barrier(0); } while (0)

// Fire-and-forget LDS atomics (ds_add no-return): no ds_read/lgkmcnt chain, no
// duplicate-bin merge, minimal VGPR temps. Bank = t%32 -> conflict-free.
__device__ __forceinline__ void scatter4(unsigned* histT, vfloat4 p, vint4 l) {
    int b0, b1, b2, b3;
    unsigned k0 = pack_elem(p.x, l.x, &b0);
    unsigned k1 = pack_elem(p.y, l.y, &b1);
    unsigned k2 = pack_elem(p.z, l.z, &b2);
    unsigned k3 = pack_elem(p.w, l.w, &b3);
    atomicAdd(&histT[b0 << 8], k0);
    atomicAdd(&histT[b1 << 8], k1);
    atomicAdd(&histT[b2 << 8], k2);
    atomicAdd(&histT[b3 << 8], k3);
}

__device__ __forceinline__ void consume(const Batch& b, unsigned* histT) {
    scatter4(histT, b.p0, b.l0);
    scatter4(histT, b.p1, b.l1);
    scatter4(histT, b.p2, b.l2);
    scatter4(histT, b.p3, b.l3);
}

__global__ __launch_bounds__(NT, 6) void ece_partial(
    const float* __restrict__ probs, const int* __restrict__ labels,
    float* __restrict__ ws, int n)
{
    __shared__ unsigned hist[16 * NT];   // 16 KB: cell[bin][t]
    const int t = threadIdx.x;

    uint4* h4 = (uint4*)hist;
#pragma unroll
    for (int i = 0; i < 4; ++i) h4[i * NT + t] = uint4{0u, 0u, 0u, 0u};
    __syncthreads();

    const int base = blockIdx.x * 16384;         // floats (4096 float4 per block)
    const float* __restrict__ p_blk = probs + base;
    const int*   __restrict__ l_blk = labels + base;
    unsigned* histT = hist + t;
    const unsigned t16 = (unsigned)t << 4;       // byte voffset for lane

    if (base + 16384 <= n) {
        // 2-deep double buffer, 8 loads per batch, hand-counted vmcnt:
        //   issue A, issue B (16 outstanding) -> vmcnt(8) => A landed
        //   consume A, issue A' -> vmcnt(8) => B landed ... etc. B' drains at vmcnt(0).
        Batch A, B;
        load_batch(A, p_blk, l_blk, t16);
        load_batch(B, p_blk, l_blk, t16 + 16384u);
        WAIT_VM8();                  // A ready, B in flight
        consume(A, histT);
        load_batch(A, p_blk, l_blk, t16 + 32768u);
        WAIT_VM8();                  // B ready, A' in flight
        consume(B, histT);
        load_batch(B, p_blk, l_blk, t16 + 49152u);
        WAIT_VM8();                  // A' ready, B' in flight
        consume(A, histT);
        WAIT_VM0();                  // B' ready
        consume(B, histT);
    } else {
        // guarded tail path (unused at N=2^25; kept for generality)
        const vfloat4* __restrict__ p4 = (const vfloat4*)p_blk;
        const vint4*   __restrict__ l4 = (const vint4*)l_blk;
        for (int j = 0; j < 16; ++j) {
            const int idx = (j << 8) + t;
            if (base + idx * 4 < n) {
                vfloat4 p = p4[idx];
                vint4   l = l4[idx];
                scatter4(histT, p, l);
            }
        }
    }
    __syncthreads();

    // cross-thread reduce: row r = t>>4 (0..15), strip s = t&15 (16 cells each)
    const int r = t >> 4, s = t & 15;
    float csum = 0.f, asum = 0.f, rsum = 0.f;
#pragma unroll
    for (int k = 0; k < 16; ++k) {
        unsigned v = hist[(r << 8) + (s << 4) + k];
        asum += (float)(v >> 24);
        csum += (float)((v >> 16) & 0xFFu);
        rsum += (float)(v & 0xFFFFu);
    }
#pragma unroll
    for (int o = 8; o; o >>= 1) {    // 16-lane strips are wave-aligned
        csum += __shfl_down(csum, o);
        asum += __shfl_down(asum, o);
        rsum += __shfl_down(rsum, o);
    }
    if (s == 0 && r < NUM_BINS) {
        float conf = fmaf(csum, (float)r * INV15, rsum * 2.44140625e-4f);
        ws[r * NB + blockIdx.x]                  = csum;
        ws[(NUM_BINS + r) * NB + blockIdx.x]     = asum;
        ws[(2 * NUM_BINS + r) * NB + blockIdx.x] = conf;
    }
}

// Final: 16 waves reduce the [45][NB] partials (360 KB) and emit scalar ECE.
__global__ __launch_bounds__(1024) void ece_final(
    const float* __restrict__ ws, float* __restrict__ out, float n)
{
    __shared__ float sums[NCOMP];
    const int wave = threadIdx.x >> 6;
    const int lane = threadIdx.x & 63;

    for (int c = wave; c < NCOMP; c += 16) {
        const float4* row4 = (const float4*)(ws + c * NB);
        float s = 0.f;
#pragma unroll
        for (int k = 0; k < NB / 256; ++k) {
            float4 v = row4[lane + (k << 6)];
            s += (v.x + v.y) + (v.z + v.w);
        }
#pragma unroll
        for (int o = 32; o; o >>= 1) s += __shfl_down(s, o);
        if (lane == 0) sums[c] = s;
    }
    __syncthreads();

    if (threadIdx.x == 0) {
        float ece = 0.f;
#pragma unroll
        for (int b = 0; b < NUM_BINS; ++b) {
            float cnt = sums[b];
            float acc = sums[NUM_BINS + b];
            float cf  = sums[2 * NUM_BINS + b];
            float denom = fmaxf(cnt, 1.f);
            ece += (cnt / n) * fabsf(acc / denom - cf / denom);
        }
        out[0] = ece;
    }
}

extern "C" void kernel_launch(void* const* d_in, const int* in_sizes, int n_in,
                              void* d_out, int out_size, void* d_ws, size_t ws_size,
                              hipStream_t stream)
{
    const float* probs  = (const float*)d_in[0];
    const int*   labels = (const int*)d_in[1];
    const int n = in_sizes[0];   // 33,554,432

    ece_partial<<<NB, NT, 0, stream>>>(probs, labels, (float*)d_ws, n);
    ece_final<<<1, 1024, 0, stream>>>((const float*)d_ws, (float*)d_out, (float)n);
}

// Round 4
// 282.856 us; speedup vs baseline: 1.4341x; 1.0025x over previous
//
#include <hip/hip_runtime.h>

#define NUM_BINS 15
#define NB 2048            // blocks; each owns a contiguous 16384-float chunk (64 KB/array)
#define NT 256
#define NCOMP 45           // ws rows: cnt[15] | acc[15] | conf[15]
#define INV15 0.066666667f
#define DEPTH 4            // staging ring slots (batches in flight)
#define NBATCH 16          // batches per block: 16 x 4 KB per array

// native clang vector types
typedef float vfloat4 __attribute__((ext_vector_type(4)));
typedef int   vint4   __attribute__((ext_vector_type(4)));

typedef const __attribute__((address_space(1))) void* gas_ptr;
typedef __attribute__((address_space(3))) void*       las_ptr;

// One uint32 per element: [31:24] label, [23:16] 1, [15:0] round((p-bin/15)*4096).
// Cell shared by 2 threads (t, t+128): cnt<=128, acc<=128, res<=128*274=35072 -> no overflow.
__device__ __forceinline__ unsigned pack_elem(float pv, int lv, int* bin_out) {
    int bin = (int)ceilf(pv * 15.0f) - 1;      // matches jnp ceil(p*15)-1 in fp32
    bin = (min(max(bin, -1), 15)) & 15;        // invalid (p<=0 | p>1) -> 15 (dump row)
    *bin_out = bin;
    float x = fmaf(pv, 4096.0f, fmaf((float)bin, -4096.0f * INV15, 0.5f));
    unsigned rq = (unsigned)x;                 // v_cvt_u32_f32 saturates negatives to 0
    return ((unsigned)lv << 24) + 0x10000u + rq;
}

// Fire-and-forget LDS atomics; hist is [16][128], cell col = t&127.
// Bank = (t&31): 2 lanes/bank within a wave -> free (m136).
__device__ __forceinline__ void scatter4(unsigned* histT, vfloat4 p, vint4 l) {
    int b0, b1, b2, b3;
    unsigned k0 = pack_elem(p.x, l.x, &b0);
    unsigned k1 = pack_elem(p.y, l.y, &b1);
    unsigned k2 = pack_elem(p.z, l.z, &b2);
    unsigned k3 = pack_elem(p.w, l.w, &b3);
    atomicAdd(&histT[b0 << 7], k0);
    atomicAdd(&histT[b1 << 7], k1);
    atomicAdd(&histT[b2 << 7], k2);
    atomicAdd(&histT[b3 << 7], k3);
}

// Counted vmcnt + sched_barrier fence (rule #18): never drain to 0 mid-loop (T4).
#define WAITV(N) do { asm volatile("s_waitcnt vmcnt(" #N ")" ::: "memory"); \
                      __builtin_amdgcn_sched_barrier(0); } while (0)

__global__ __launch_bounds__(NT, 4) void ece_partial(
    const float* __restrict__ probs, const int* __restrict__ labels,
    float* __restrict__ ws, int n)
{
    __shared__ unsigned hist[16 * 128];       // 8 KB: cell[bin][t&127]
    __shared__ unsigned stage[DEPTH * 2048];  // 32 KB ring: slot = 4KB probs | 4KB labels
    const int t = threadIdx.x;

    uint4* h4 = (uint4*)hist;                 // zero 8 KB = 512 uint4
    h4[t]       = uint4{0u, 0u, 0u, 0u};
    h4[t + 256] = uint4{0u, 0u, 0u, 0u};
    __syncthreads();

    const int base = blockIdx.x * 16384;      // floats
    const float* __restrict__ p_blk = probs + base;
    const int*   __restrict__ l_blk = labels + base;
    unsigned* histT = hist + (t & 127);
    const int wbase = (t >> 6) << 8;          // wave-uniform LDS sub-base (uints)

    // global_load_lds staging: in-flight data lives in LDS, not VGPRs (r2/r3 both
    // collapsed trying to keep it register-resident). LDS dest is wave-uniform
    // base + lane*16 (m104); each wave consumes exactly the region it loaded, so
    // the main loop needs NO barriers — every wave free-runs on its own vmcnt.
    // Cached (aux=0): replay FETCH_SIZE=3MB proves inputs are L3-hot post-restore.
#define ISSUE(j) do {                                                          \
        __builtin_amdgcn_global_load_lds(                                      \
            (gas_ptr)(p_blk + (j) * 1024 + t * 4),                             \
            (las_ptr)&stage[(((j) & (DEPTH - 1)) << 11) + wbase], 16, 0, 0);   \
        __builtin_amdgcn_global_load_lds(                                      \
            (gas_ptr)(l_blk + (j) * 1024 + t * 4),                             \
            (las_ptr)&stage[(((j) & (DEPTH - 1)) << 11) + 1024 + wbase], 16, 0, 0); \
    } while (0)

    // ds_read_b128 lane-linear (conflict-free); pack consumes data (implicit
    // lgkmcnt wait) BEFORE the next ISSUE overwrites this slot -> no WAR race.
#define CONSUME(j) do {                                                        \
        const int slot = ((j) & (DEPTH - 1)) << 11;                            \
        vfloat4 p = *(const vfloat4*)&stage[slot + t * 4];                     \
        vint4   l = *(const vint4*)&stage[slot + 1024 + t * 4];                \
        scatter4(histT, p, l);                                                 \
    } while (0)

    if (base + 16384 <= n) {
        ISSUE(0); ISSUE(1); ISSUE(2); ISSUE(3);          // 8 outstanding
        WAITV(6); CONSUME(0);  ISSUE(4);
        WAITV(6); CONSUME(1);  ISSUE(5);
        WAITV(6); CONSUME(2);  ISSUE(6);
        WAITV(6); CONSUME(3);  ISSUE(7);
        WAITV(6); CONSUME(4);  ISSUE(8);
        WAITV(6); CONSUME(5);  ISSUE(9);
        WAITV(6); CONSUME(6);  ISSUE(10);
        WAITV(6); CONSUME(7);  ISSUE(11);
        WAITV(6); CONSUME(8);  ISSUE(12);
        WAITV(6); CONSUME(9);  ISSUE(13);
        WAITV(6); CONSUME(10); ISSUE(14);
        WAITV(6); CONSUME(11); ISSUE(15);
        WAITV(6); CONSUME(12);                           // drain: 6 left
        WAITV(4); CONSUME(13);
        WAITV(2); CONSUME(14);
        WAITV(0); CONSUME(15);
    } else {
        // guarded tail path (unused at N=2^25; kept for generality)
        const vfloat4* __restrict__ p4 = (const vfloat4*)p_blk;
        const vint4*   __restrict__ l4 = (const vint4*)l_blk;
        for (int j = 0; j < 16; ++j) {
            const int idx = (j << 8) + t;
            if (base + idx * 4 < n) {
                vfloat4 p = p4[idx];
                vint4   l = l4[idx];
                scatter4(histT, p, l);
            }
        }
    }
    __syncthreads();

    // cross-thread reduce over 128 cols: row r = t>>4 (0..15), strip s = t&15 (8 cells)
    const int r = t >> 4, s = t & 15;
    float csum = 0.f, asum = 0.f, rsum = 0.f;
#pragma unroll
    for (int k = 0; k < 8; ++k) {
        unsigned v = hist[(r << 7) + (s << 3) + k];
        asum += (float)(v >> 24);
        csum += (float)((v >> 16) & 0xFFu);
        rsum += (float)(v & 0xFFFFu);
    }
#pragma unroll
    for (int o = 8; o; o >>= 1) {    // 16-lane strips are wave-aligned
        csum += __shfl_down(csum, o);
        asum += __shfl_down(asum, o);
        rsum += __shfl_down(rsum, o);
    }
    if (s == 0 && r < NUM_BINS) {
        float conf = fmaf(csum, (float)r * INV15, rsum * 2.44140625e-4f);
        ws[r * NB + blockIdx.x]                  = csum;
        ws[(NUM_BINS + r) * NB + blockIdx.x]     = asum;
        ws[(2 * NUM_BINS + r) * NB + blockIdx.x] = conf;
    }
}

// Final: 16 waves reduce the [45][NB] partials (360 KB) and emit scalar ECE.
__global__ __launch_bounds__(1024) void ece_final(
    const float* __restrict__ ws, float* __restrict__ out, float n)
{
    __shared__ float sums[NCOMP];
    const int wave = threadIdx.x >> 6;
    const int lane = threadIdx.x & 63;

    for (int c = wave; c < NCOMP; c += 16) {
        const float4* row4 = (const float4*)(ws + c * NB);
        float s = 0.f;
#pragma unroll
        for (int k = 0; k < NB / 256; ++k) {
            float4 v = row4[lane + (k << 6)];
            s += (v.x + v.y) + (v.z + v.w);
        }
#pragma unroll
        for (int o = 32; o; o >>= 1) s += __shfl_down(s, o);
        if (lane == 0) sums[c] = s;
    }
    __syncthreads();

    if (threadIdx.x == 0) {
        float ece = 0.f;
#pragma unroll
        for (int b = 0; b < NUM_BINS; ++b) {
            float cnt = sums[b];
            float acc = sums[NUM_BINS + b];
            float cf  = sums[2 * NUM_BINS + b];
            float denom = fmaxf(cnt, 1.f);
            ece += (cnt / n) * fabsf(acc / denom - cf / denom);
        }
        out[0] = ece;
    }
}

extern "C" void kernel_launch(void* const* d_in, const int* in_sizes, int n_in,
                              void* d_out, int out_size, void* d_ws, size_t ws_size,
                              hipStream_t stream)
{
    const float* probs  = (const float*)d_in[0];
    const int*   labels = (const int*)d_in[1];
    const int n = in_sizes[0];   // 33,554,432

    ece_partial<<<NB, NT, 0, stream>>>(probs, labels, (float*)d_ws, n);
    ece_final<<<1, 1024, 0, stream>>>((const float*)d_ws, (float*)d_out, (float)n);
}

// Round 5
// 282.554 us; speedup vs baseline: 1.4356x; 1.0011x over previous
//
#include <hip/hip_runtime.h>

#define NUM_BINS 15
#define NB 2048            // blocks; each owns a contiguous 4096-float4 chunk (64 KB/array)
#define NT 256
#define NCOMP 45           // ws rows: cnt[15] | acc[15] | conf[15]
#define INV15 0.066666667f

// native clang vector types
typedef float vfloat4 __attribute__((ext_vector_type(4)));
typedef int   vint4   __attribute__((ext_vector_type(4)));

// One uint32 per element: [31:24] label, [23:16] 1, [15:0] round((p-bin/15)*4096).
// Per-thread totals (64 elem): cnt<=64, acc<=64, res<=64*274=17536 -> no field overflow.
__device__ __forceinline__ unsigned pack_elem(float pv, int lv, int* bin_out) {
    int bin = (int)ceilf(pv * 15.0f) - 1;      // matches jnp ceil(p*15)-1 in fp32
    bin = (min(max(bin, -1), 15)) & 15;        // invalid (p<=0 | p>1) -> 15 (dump row)
    *bin_out = bin;
    float x = fmaf(pv, 4096.0f, fmaf((float)bin, -4096.0f * INV15, 0.5f));
    unsigned rq = (unsigned)x;                 // v_cvt_u32_f32 saturates negatives to 0
    return ((unsigned)lv << 24) + 0x10000u + rq;
}

struct Batch { vfloat4 p0, p1, p2, p3; vint4 l0, l1, l2, l3; };

// CACHED loads (no nontemporal): the harness restore-copy rewrites both arrays
// immediately before each iteration, so they are L3-resident (proven: cached
// variants FETCH 131 of 268 MB; round-3 replays FETCH 3 MB). r0's nt loads
// bypassed that and paid full HBM price.
__device__ __forceinline__ void load_batch(Batch& b, const vfloat4* __restrict__ p4,
                                           const vint4* __restrict__ l4, int j, int t) {
    const int o = (j << 10) + t;
    b.p0 = p4[o];
    b.p1 = p4[o + 256];
    b.p2 = p4[o + 512];
    b.p3 = p4[o + 768];
    b.l0 = l4[o];
    b.l1 = l4[o + 256];
    b.l2 = l4[o + 512];
    b.l3 = l4[o + 768];
}

// Keep-alive pin (rule #17): demands all 8 loaded values in VGPRs at this point.
// Plain loads are rematerializable and RA sank them in round 2 (VGPR collapsed
// to 24, pipeline died). The pin makes sinking impossible; the compiler inserts
// its own COUNTED s_waitcnt vmcnt(8) here (normal G7 behavior) — r0's pipeline,
// but with L3-visible loads and no hand-rolled waitcnt (round-3/4 failure mode).
#define PIN(b) asm volatile("" : "+v"(b.p0), "+v"(b.p1), "+v"(b.p2), "+v"(b.p3), \
                                 "+v"(b.l0), "+v"(b.l1), "+v"(b.l2), "+v"(b.l3))

// Fire-and-forget LDS atomics (ds_add no-return): no ds_read/lgkmcnt chain, no
// duplicate-bin merge, minimal VGPR temps. hist[bin][t]: bank = t%32, 2-way
// wave64 aliasing is free (m136); bin<<8 keeps bank independent of bin.
__device__ __forceinline__ void scatter4(unsigned* histT, vfloat4 p, vint4 l) {
    int b0, b1, b2, b3;
    unsigned k0 = pack_elem(p.x, l.x, &b0);
    unsigned k1 = pack_elem(p.y, l.y, &b1);
    unsigned k2 = pack_elem(p.z, l.z, &b2);
    unsigned k3 = pack_elem(p.w, l.w, &b3);
    atomicAdd(&histT[b0 << 8], k0);
    atomicAdd(&histT[b1 << 8], k1);
    atomicAdd(&histT[b2 << 8], k2);
    atomicAdd(&histT[b3 << 8], k3);
}

__device__ __forceinline__ void consume(const Batch& b, unsigned* histT) {
    scatter4(histT, b.p0, b.l0);
    scatter4(histT, b.p1, b.l1);
    scatter4(histT, b.p2, b.l2);
    scatter4(histT, b.p3, b.l3);
}

// __launch_bounds__(256,5): VGPR cap ~102 (vs 84 at 6). Demand is ~64 data + ~25
// temps; the extra headroom insures against the round-3 spill catastrophe at the
// cost of 24->20 waves/CU — irrelevant for a BW-bound loop.
__global__ __launch_bounds__(NT, 5) void ece_partial(
    const float* __restrict__ probs, const int* __restrict__ labels,
    float* __restrict__ ws, int n4)
{
    __shared__ unsigned hist[16 * NT];   // 16 KB: cell[bin][t]
    const int t = threadIdx.x;

    uint4* h4 = (uint4*)hist;
#pragma unroll
    for (int i = 0; i < 4; ++i) h4[i * NT + t] = uint4{0u, 0u, 0u, 0u};
    __syncthreads();

    const int base = blockIdx.x * 4096;          // float4 units
    const vfloat4* __restrict__ p4 = (const vfloat4*)probs + base;
    const vint4*   __restrict__ l4 = (const vint4*)labels + base;
    unsigned* histT = hist + t;

    if (base + 4096 <= n4) {
        // r0's double-buffered pipeline: 8 loads of batch j+1 in flight while
        // batch j is consumed. sched_barrier(0) pins region order; PIN forces
        // materialization (compiler emits counted vmcnt(8) waits at each PIN).
        Batch A, B;
        load_batch(A, p4, l4, 0, t);
        load_batch(B, p4, l4, 1, t);
        __builtin_amdgcn_sched_barrier(0);
        PIN(A);                                  // waits A (8 in flight: B)
        consume(A, histT);
        load_batch(A, p4, l4, 2, t);
        __builtin_amdgcn_sched_barrier(0);
        PIN(B);                                  // waits B (8 in flight: A')
        consume(B, histT);
        load_batch(B, p4, l4, 3, t);
        __builtin_amdgcn_sched_barrier(0);
        PIN(A);                                  // waits A' (8 in flight: B')
        consume(A, histT);
        PIN(B);                                  // waits B' (drain)
        consume(B, histT);
    } else {
        // guarded tail path (unused at N=2^25; kept for generality)
        for (int j = 0; j < 16; ++j) {
            const int idx = (j << 8) + t;
            if (base + idx < n4) {
                vfloat4 p = p4[idx];
                vint4   l = l4[idx];
                scatter4(histT, p, l);
            }
        }
    }
    __syncthreads();

    // cross-thread reduce: row r = t>>4 (0..15), strip s = t&15 (16 cells each)
    const int r = t >> 4, s = t & 15;
    float csum = 0.f, asum = 0.f, rsum = 0.f;
#pragma unroll
    for (int k = 0; k < 16; ++k) {
        unsigned v = hist[(r << 8) + (s << 4) + k];
        asum += (float)(v >> 24);
        csum += (float)((v >> 16) & 0xFFu);
        rsum += (float)(v & 0xFFFFu);
    }
#pragma unroll
    for (int o = 8; o; o >>= 1) {    // 16-lane strips are wave-aligned
        csum += __shfl_down(csum, o);
        asum += __shfl_down(asum, o);
        rsum += __shfl_down(rsum, o);
    }
    if (s == 0 && r < NUM_BINS) {
        float conf = fmaf(csum, (float)r * INV15, rsum * 2.44140625e-4f);
        ws[r * NB + blockIdx.x]                  = csum;
        ws[(NUM_BINS + r) * NB + blockIdx.x]     = asum;
        ws[(2 * NUM_BINS + r) * NB + blockIdx.x] = conf;
    }
}

// Final: 16 waves reduce the [45][NB] partials (360 KB) and emit scalar ECE.
__global__ __launch_bounds__(1024) void ece_final(
    const float* __restrict__ ws, float* __restrict__ out, float n)
{
    __shared__ float sums[NCOMP];
    const int wave = threadIdx.x >> 6;
    const int lane = threadIdx.x & 63;

    for (int c = wave; c < NCOMP; c += 16) {
        const float4* row4 = (const float4*)(ws + c * NB);
        float s = 0.f;
#pragma unroll
        for (int k = 0; k < NB / 256; ++k) {
            float4 v = row4[lane + (k << 6)];
            s += (v.x + v.y) + (v.z + v.w);
        }
#pragma unroll
        for (int o = 32; o; o >>= 1) s += __shfl_down(s, o);
        if (lane == 0) sums[c] = s;
    }
    __syncthreads();

    if (threadIdx.x == 0) {
        float ece = 0.f;
#pragma unroll
        for (int b = 0; b < NUM_BINS; ++b) {
            float cnt = sums[b];
            float acc = sums[NUM_BINS + b];
            float cf  = sums[2 * NUM_BINS + b];
            float denom = fmaxf(cnt, 1.f);
            ece += (cnt / n) * fabsf(acc / denom - cf / denom);
        }
        out[0] = ece;
    }
}

extern "C" void kernel_launch(void* const* d_in, const int* in_sizes, int n_in,
                              void* d_out, int out_size, void* d_ws, size_t ws_size,
                              hipStream_t stream)
{
    const float* probs  = (const float*)d_in[0];
    const int*   labels = (const int*)d_in[1];
    const int n = in_sizes[0];   // 33,554,432

    ece_partial<<<NB, NT, 0, stream>>>(probs, labels, (float*)d_ws, n / 4);
    ece_final<<<1, 1024, 0, stream>>>((const float*)d_ws, (float*)d_out, (float)n);
}

// Round 8
// 255.497 us; speedup vs baseline: 1.5876x; 1.1059x over previous
//
#include <hip/hip_runtime.h>

#define NUM_BINS 15
#define NB 2048            // blocks; each owns a contiguous 4096-float4 chunk (64 KB/array)
#define NT 256
#define NCOMP 45           // ws rows: cnt[15] | acc[15] | conf[15]
#define INV15 0.066666667f

// native clang vector types — required by __builtin_nontemporal_load
typedef float vfloat4 __attribute__((ext_vector_type(4)));
typedef int   vint4   __attribute__((ext_vector_type(4)));

// One uint32 per element: [31:24] label, [23:16] 1, [15:0] round((p-bin/15)*4096).
// Per-thread totals (64 elem): cnt<=64, acc<=64, res<=64*274=17536 -> no field overflow.
__device__ __forceinline__ unsigned pack_elem(float pv, int lv, int* bin_out) {
    int bin = (int)ceilf(pv * 15.0f) - 1;      // matches jnp ceil(p*15)-1 in fp32
    bin = (min(max(bin, -1), 15)) & 15;        // invalid (p<=0 | p>1) -> 15 (dump row)
    *bin_out = bin;
    float x = fmaf(pv, 4096.0f, fmaf((float)bin, -4096.0f * INV15, 0.5f));
    unsigned rq = (unsigned)x;                 // v_cvt_u32_f32 saturates negatives to 0
    return ((unsigned)lv << 24) + 0x10000u + rq;
}

struct Batch { vfloat4 p0, p1, p2, p3; vint4 l0, l1, l2, l3; };

// Nontemporal loads: the proven-fast path for this harness (74.8 µs partial vs
// 103-106 µs for every cached variant). The restore-copy leaves inputs dirty in
// L3; nt reads hit without allocating (no eviction/writeback storm), while
// cached reads trigger allocate-on-miss evictions and sustain only ~2.6 TB/s.
// nt builtin loads are also not rematerialized by RA (unlike plain loads, which
// collapsed the double-buffer in rounds 2/5).
__device__ __forceinline__ void load_batch(Batch& b, const vfloat4* __restrict__ p4,
                                           const vint4* __restrict__ l4, int j, int t) {
    const int o = (j << 10) + t;
    b.p0 = __builtin_nontemporal_load(&p4[o]);
    b.p1 = __builtin_nontemporal_load(&p4[o + 256]);
    b.p2 = __builtin_nontemporal_load(&p4[o + 512]);
    b.p3 = __builtin_nontemporal_load(&p4[o + 768]);
    b.l0 = __builtin_nontemporal_load(&l4[o]);
    b.l1 = __builtin_nontemporal_load(&l4[o + 256]);
    b.l2 = __builtin_nontemporal_load(&l4[o + 512]);
    b.l3 = __builtin_nontemporal_load(&l4[o + 768]);
}

// Gather-merge-scatter for 4 elements: 4 independent ds_reads, register-level
// duplicate-bin merge (last write carries the full sum), 4 ds_writes.
__device__ __forceinline__ void scatter4(unsigned* histT, vfloat4 p, vint4 l) {
    int b0, b1, b2, b3;
    unsigned k0 = pack_elem(p.x, l.x, &b0);
    unsigned k1 = pack_elem(p.y, l.y, &b1);
    unsigned k2 = pack_elem(p.z, l.z, &b2);
    unsigned k3 = pack_elem(p.w, l.w, &b3);
    unsigned c0 = histT[b0 << 8];
    unsigned c1 = histT[b1 << 8];
    unsigned c2 = histT[b2 << 8];
    unsigned c3 = histT[b3 << 8];
    // duplicate-bin merge: equal-bin elements read the same c; the LAST write to
    // an address must carry the sum of all k's for that bin.
    const bool e10 = (b1 == b0), e20 = (b2 == b0), e21 = (b2 == b1);
    const bool e30 = (b3 == b0), e31 = (b3 == b1), e32 = (b3 == b2);
    unsigned m1 = k1 + (e10 ? k0 : 0u);
    unsigned m2 = k2 + (e21 ? m1 : 0u) + ((e20 && !e10) ? k0 : 0u);
    unsigned m3 = k3 + (e32 ? m2 : 0u) + ((e31 && !e21) ? m1 : 0u)
                     + ((e30 && !e20 && !e10) ? k0 : 0u);
    histT[b0 << 8] = c0 + k0;
    histT[b1 << 8] = c1 + m1;
    histT[b2 << 8] = c2 + m2;
    histT[b3 << 8] = c3 + m3;
}

__device__ __forceinline__ void consume(const Batch& b, unsigned* histT) {
    scatter4(histT, b.p0, b.l0);
    scatter4(histT, b.p1, b.l1);
    scatter4(histT, b.p2, b.l2);
    scatter4(histT, b.p3, b.l3);
}

__global__ __launch_bounds__(NT, 6) void ece_partial(
    const float* __restrict__ probs, const int* __restrict__ labels,
    float* __restrict__ ws, int n4)
{
    __shared__ unsigned hist[16 * NT];   // 16 KB: cell[bin][t], bank = t%32, conflict-free
    const int t = threadIdx.x;

    uint4* h4 = (uint4*)hist;
#pragma unroll
    for (int i = 0; i < 4; ++i) h4[i * NT + t] = uint4{0u, 0u, 0u, 0u};
    __syncthreads();

    const int base = blockIdx.x * 4096;          // float4 units
    const vfloat4* __restrict__ p4 = (const vfloat4*)probs + base;
    const vint4*   __restrict__ l4 = (const vint4*)labels + base;
    unsigned* histT = hist + t;

    if (base + 4096 <= n4) {
        // double-buffered pipeline: batch j+1's 8 loads are in flight while batch j
        // is consumed; sched_barrier(0) pins the issue order.
        Batch A, B;
        load_batch(A, p4, l4, 0, t);
        load_batch(B, p4, l4, 1, t);
        __builtin_amdgcn_sched_barrier(0);
        consume(A, histT);
        load_batch(A, p4, l4, 2, t);
        __builtin_amdgcn_sched_barrier(0);
        consume(B, histT);
        load_batch(B, p4, l4, 3, t);
        __builtin_amdgcn_sched_barrier(0);
        consume(A, histT);
        consume(B, histT);
    } else {
        // guarded tail path (unused at N=2^25; kept for generality)
        for (int j = 0; j < 16; ++j) {
            const int idx = (j << 8) + t;
            if (base + idx < n4) {
                vfloat4 p = p4[idx];
                vint4   l = l4[idx];
                scatter4(histT, p, l);
            }
        }
    }
    __syncthreads();

    // cross-thread reduce: row r = t>>4 (0..15), strip s = t&15 (16 cells each)
    const int r = t >> 4, s = t & 15;
    float csum = 0.f, asum = 0.f, rsum = 0.f;
#pragma unroll
    for (int k = 0; k < 16; ++k) {
        unsigned v = hist[(r << 8) + (s << 4) + k];
        asum += (float)(v >> 24);
        csum += (float)((v >> 16) & 0xFFu);
        rsum += (float)(v & 0xFFFFu);
    }
#pragma unroll
    for (int o = 8; o; o >>= 1) {    // 16-lane strips are wave-aligned
        csum += __shfl_down(csum, o);
        asum += __shfl_down(asum, o);
        rsum += __shfl_down(rsum, o);
    }
    if (s == 0 && r < NUM_BINS) {
        float conf = fmaf(csum, (float)r * INV15, rsum * 2.44140625e-4f);
        ws[r * NB + blockIdx.x]                  = csum;
        ws[(NUM_BINS + r) * NB + blockIdx.x]     = asum;
        ws[(2 * NUM_BINS + r) * NB + blockIdx.x] = conf;
    }
}

// Final: 16 waves reduce the [45][NB] partials (360 KB) and emit scalar ECE.
__global__ __launch_bounds__(1024) void ece_final(
    const float* __restrict__ ws, float* __restrict__ out, float n)
{
    __shared__ float sums[NCOMP];
    const int wave = threadIdx.x >> 6;
    const int lane = threadIdx.x & 63;

    for (int c = wave; c < NCOMP; c += 16) {
        const float4* row4 = (const float4*)(ws + c * NB);
        float s = 0.f;
#pragma unroll
        for (int k = 0; k < NB / 256; ++k) {
            float4 v = row4[lane + (k << 6)];
            s += (v.x + v.y) + (v.z + v.w);
        }
#pragma unroll
        for (int o = 32; o; o >>= 1) s += __shfl_down(s, o);
        if (lane == 0) sums[c] = s;
    }
    __syncthreads();

    if (threadIdx.x == 0) {
        float ece = 0.f;
#pragma unroll
        for (int b = 0; b < NUM_BINS; ++b) {
            float cnt = sums[b];
            float acc = sums[NUM_BINS + b];
            float cf  = sums[2 * NUM_BINS + b];
            float denom = fmaxf(cnt, 1.f);
            ece += (cnt / n) * fabsf(acc / denom - cf / denom);
        }
        out[0] = ece;
    }
}

extern "C" void kernel_launch(void* const* d_in, const int* in_sizes, int n_in,
                              void* d_out, int out_size, void* d_ws, size_t ws_size,
                              hipStream_t stream)
{
    const float* probs  = (const float*)d_in[0];
    const int*   labels = (const int*)d_in[1];
    const int n = in_sizes[0];   // 33,554,432

    ece_partial<<<NB, NT, 0, stream>>>(probs, labels, (float*)d_ws, n / 4);
    ece_final<<<1, 1024, 0, stream>>>((const float*)d_ws, (float*)d_out, (float)n);
}